// Round 8
// baseline (229.259 us; speedup 1.0000x reference)
//
#include <hip/hip_runtime.h>
#include <hip/hip_bf16.h>

#define NNODES  50000
#define NSAMP   25
#define FEAT    128
#define TABROWS 100000

typedef __attribute__((ext_vector_type(4))) float  f32x4;
typedef __attribute__((ext_vector_type(2))) float  f32x2;
typedef __attribute__((ext_vector_type(8))) __bf16 bf16x8;

__device__ __forceinline__ bf16x8 cvt2(const f32x4 lo, const f32x4 hi) {
  bf16x8 r;
  r[0] = (__bf16)lo[0]; r[1] = (__bf16)lo[1];
  r[2] = (__bf16)lo[2]; r[3] = (__bf16)lo[3];
  r[4] = (__bf16)hi[0]; r[5] = (__bf16)hi[1];
  r[6] = (__bf16)hi[2]; r[7] = (__bf16)hi[3];
  return r;
}

// Pass 1: fp32 table -> bf16 table in workspace (halves gather traffic).
__global__ __launch_bounds__(256)
void cvt_table_kernel(const float* __restrict__ src, __bf16* __restrict__ dst, int n8)
{
  int i = blockIdx.x * blockDim.x + threadIdx.x;
  const int stride = gridDim.x * blockDim.x;
  for (; i < n8; i += stride) {
    f32x4 lo = ((const f32x4*)src)[2 * i];
    f32x4 hi = ((const f32x4*)src)[2 * i + 1];
    ((bf16x8*)dst)[i] = cvt2(lo, hi);
  }
}

// Pass 2: wave-per-node, occupancy-first (R4 structure, 512-thread blocks).
//   out[n,f] = (1/25) * sum_s relu(e[nbr[n,s],:] @ W[f,:] + b[f])
// 8 waves share ONE 32 KB B-copy (=W^T in MFMA fragment layout) -> LDS/block
// 36 KB -> 4 blocks/CU x 8 waves = 32 waves/CU occupancy budget (R4's 4-wave
// blocks capped at 16). Per-wave loop is R4's verified 52-VGPR schedule: the
// compiler refuses source-level pipelining (R5/R6: spills/sinks), so latency
// hiding comes from wave count. Bias folded into MFMA C-in; pad rows (s>=25)
// gathered as zero, their relu(bias) contribution subtracted after reduce.
// Output staged through wave-private LDS -> one coalesced 512 B store/node.
// mfma_f32_16x16x32_bf16; C/D: col=lane&15, row=(lane>>4)*4+reg.
template<int BF16TAB>
__global__ __launch_bounds__(512, 8)
void meanpool_mfma_kernel(const int* __restrict__ nbr,
                          const float* __restrict__ embf32,
                          const __bf16* __restrict__ embbf,
                          const float* __restrict__ W,
                          const float* __restrict__ b,
                          float* __restrict__ out)
{
  __shared__ bf16x8 Blds[8 * 4 * 64];   // 32 KB, shared by all 8 waves
  __shared__ float  Ot[8][128];         // 4 KB, per-wave transpose scratch

  const int tid  = threadIdx.x;
  const int lane = tid & 63;
  const int wib  = tid >> 6;
  const int wid  = blockIdx.x * 8 + wib;
  const int nW   = gridDim.x * 8;

  const int col  = lane & 15;   // f within f-tile (B col), s within M-tile (A row)
  const int quad = lane >> 4;   // k-subblock for A/B, row-group for D
  const int coff = quad * 8;    // element offset within a K=32 chunk

  // ---- Fill B LDS: chunk c = nt*256 + kk*64 + l holds
  //      W[nt*16 + (l&15)][kk*32 + (l>>4)*8 .. +7] as bf16x8
  for (int c = tid; c < 2048; c += 512) {
    const int nt = c >> 8;
    const int kk = (c >> 6) & 3;
    const int l  = c & 63;
    const int f  = nt * 16 + (l & 15);
    const int d0 = kk * 32 + (l >> 4) * 8;
    f32x4 lo = *(const f32x4*)(W + f * FEAT + d0);
    f32x4 hi = *(const f32x4*)(W + f * FEAT + d0 + 4);
    Blds[c] = cvt2(lo, hi);
  }

  float bias[8];
  #pragma unroll
  for (int nt = 0; nt < 8; ++nt) bias[nt] = b[nt * 16 + col];

  __syncthreads();

  const float inv = 1.0f / (float)NSAMP;
  const bool  v1 = col < 9;              // tile-1 row (16+col) valid iff col<9
  const bf16x8 zero8 = {};
  float* osc = &Ot[wib][0];

  for (int n = wid; n < NNODES; n += nW) {
    const int* nb = nbr + n * NSAMP;
    const int i0 = nb[col];
    const int i1 = v1 ? nb[16 + col] : 0;

    // ---- Gather A fragments directly in MFMA layout (16 B per lane per kk)
    bf16x8 A0[4], A1[4];
    if (BF16TAB) {
      const __bf16* r0 = embbf + (long long)i0 * FEAT + coff;
      const __bf16* r1 = embbf + (long long)i1 * FEAT + coff;
      #pragma unroll
      for (int kk = 0; kk < 4; ++kk) {
        A0[kk] = *(const bf16x8*)(r0 + kk * 32);
        A1[kk] = v1 ? *(const bf16x8*)(r1 + kk * 32) : zero8;
      }
    } else {
      const float* r0 = embf32 + (long long)i0 * FEAT + coff;
      const float* r1 = embf32 + (long long)i1 * FEAT + coff;
      const f32x4 z = {0.f, 0.f, 0.f, 0.f};
      #pragma unroll
      for (int kk = 0; kk < 4; ++kk) {
        A0[kk] = cvt2(*(const f32x4*)(r0 + kk * 32), *(const f32x4*)(r0 + kk * 32 + 4));
        A1[kk] = v1 ? cvt2(*(const f32x4*)(r1 + kk * 32), *(const f32x4*)(r1 + kk * 32 + 4))
                    : cvt2(z, z);
      }
    }

    #pragma unroll
    for (int nt = 0; nt < 8; ++nt) {
      const float bn = bias[nt];
      f32x4 acc0 = {bn, bn, bn, bn};   // bias folded into C-in
      f32x4 acc1 = {bn, bn, bn, bn};
      #pragma unroll
      for (int kk = 0; kk < 4; ++kk) {
        const bf16x8 Bf = Blds[nt * 256 + kk * 64 + lane];
        acc0 = __builtin_amdgcn_mfma_f32_16x16x32_bf16(A0[kk], Bf, acc0, 0, 0, 0);
        acc1 = __builtin_amdgcn_mfma_f32_16x16x32_bf16(A1[kk], Bf, acc1, 0, 0, 0);
      }
      // relu + per-lane partial mean-pool (pad rows contribute relu(bias))
      float psum = 0.f;
      #pragma unroll
      for (int j = 0; j < 4; ++j)
        psum += fmaxf(acc0[j], 0.f) + fmaxf(acc1[j], 0.f);
      psum += __shfl_xor(psum, 16);
      psum += __shfl_xor(psum, 32);
      if (lane < 16)
        osc[nt * 16 + lane] = (psum - 7.0f * fmaxf(bn, 0.f)) * inv;
    }
    // DS ops are in-order within a wave; drain writes before transpose read
    asm volatile("s_waitcnt lgkmcnt(0)" ::: "memory");
    const f32x2 o2 = *(const f32x2*)(osc + 2 * lane);
    *(f32x2*)(out + (long long)n * FEAT + 2 * lane) = o2;  // 512 B coalesced/node
  }
}

extern "C" void kernel_launch(void* const* d_in, const int* in_sizes, int n_in,
                              void* d_out, int out_size, void* d_ws, size_t ws_size,
                              hipStream_t stream) {
  const int*   nbr = (const int*)d_in[0];
  const float* emb = (const float*)d_in[1];
  const float* W   = (const float*)d_in[2];
  const float* b   = (const float*)d_in[3];
  float* out = (float*)d_out;

  const size_t tabBytes = (size_t)TABROWS * FEAT * sizeof(__bf16);
  const bool useBf16 = ws_size >= tabBytes;

  if (useBf16) {
    __bf16* tab = (__bf16*)d_ws;
    const int n8 = TABROWS * FEAT / 8;
    hipLaunchKernelGGL(cvt_table_kernel, dim3(2048), dim3(256), 0, stream,
                       emb, tab, n8);
    hipLaunchKernelGGL((meanpool_mfma_kernel<1>), dim3(1024), dim3(512), 0, stream,
                       nbr, emb, tab, W, b, out);
  } else {
    hipLaunchKernelGGL((meanpool_mfma_kernel<0>), dim3(1024), dim3(512), 0, stream,
                       nbr, emb, (const __bf16*)nullptr, W, b, out);
  }
}

// Round 9
// 219.814 us; speedup vs baseline: 1.0430x; 1.0430x over previous
//
#include <hip/hip_runtime.h>
#include <hip/hip_bf16.h>

#define NNODES  50000
#define NSAMP   25
#define FEAT    128
#define TABROWS 100000

typedef __attribute__((ext_vector_type(4))) float  f32x4;
typedef __attribute__((ext_vector_type(2))) float  f32x2;
typedef __attribute__((ext_vector_type(8))) __bf16 bf16x8;

__device__ __forceinline__ bf16x8 cvt2(const f32x4 lo, const f32x4 hi) {
  bf16x8 r;
  r[0] = (__bf16)lo[0]; r[1] = (__bf16)lo[1];
  r[2] = (__bf16)lo[2]; r[3] = (__bf16)lo[3];
  r[4] = (__bf16)hi[0]; r[5] = (__bf16)hi[1];
  r[6] = (__bf16)hi[2]; r[7] = (__bf16)hi[3];
  return r;
}

// Pass 1: fp32 table -> bf16 table in workspace (halves gather traffic).
__global__ __launch_bounds__(256)
void cvt_table_kernel(const float* __restrict__ src, __bf16* __restrict__ dst, int n8)
{
  int i = blockIdx.x * blockDim.x + threadIdx.x;
  const int stride = gridDim.x * blockDim.x;
  for (; i < n8; i += stride) {
    f32x4 lo = ((const f32x4*)src)[2 * i];
    f32x4 hi = ((const f32x4*)src)[2 * i + 1];
    ((bf16x8*)dst)[i] = cvt2(lo, hi);
  }
}

// Pass 2: wave-per-node. R4's verified 52-VGPR per-wave loop; occupancy via
// 512-thread blocks (8 waves share ONE 32 KB B-copy in LDS).
//   out[n,f] = (1/25) * sum_s relu(e[nbr[n,s],:] @ W[f,:] + b[f])
// __launch_bounds__(512, 6): 6 waves/EU = 24 waves/CU (75%), VGPR cap ~85 --
// R8's (512,8) capped VGPR at 64 and the allocator spilled (VGPR=32, WRITE
// 100 MB scratch traffic, dur 137us). 6 waves/EU keeps the proven ~52-60 VGPR
// allocation spill-free while adding 1.5x R4's wave count for latency hiding.
// LDS: 3 blocks/CU x 36 KB = 108 KB <= 160 OK. Bias folded into MFMA C-in;
// pad rows (s>=25) gathered as zero, their relu(bias) removed after reduce.
// Output staged through wave-private LDS -> one coalesced 512 B store/node.
// mfma_f32_16x16x32_bf16; C/D: col=lane&15, row=(lane>>4)*4+reg.
template<int BF16TAB>
__global__ __launch_bounds__(512, 6)
void meanpool_mfma_kernel(const int* __restrict__ nbr,
                          const float* __restrict__ embf32,
                          const __bf16* __restrict__ embbf,
                          const float* __restrict__ W,
                          const float* __restrict__ b,
                          float* __restrict__ out)
{
  __shared__ bf16x8 Blds[8 * 4 * 64];   // 32 KB, shared by all 8 waves
  __shared__ float  Ot[8][128];         // 4 KB, per-wave transpose scratch

  const int tid  = threadIdx.x;
  const int lane = tid & 63;
  const int wib  = tid >> 6;
  const int wid  = blockIdx.x * 8 + wib;
  const int nW   = gridDim.x * 8;

  const int col  = lane & 15;   // f within f-tile (B col), s within M-tile (A row)
  const int quad = lane >> 4;   // k-subblock for A/B, row-group for D
  const int coff = quad * 8;    // element offset within a K=32 chunk

  // ---- Fill B LDS: chunk c = nt*256 + kk*64 + l holds
  //      W[nt*16 + (l&15)][kk*32 + (l>>4)*8 .. +7] as bf16x8
  for (int c = tid; c < 2048; c += 512) {
    const int nt = c >> 8;
    const int kk = (c >> 6) & 3;
    const int l  = c & 63;
    const int f  = nt * 16 + (l & 15);
    const int d0 = kk * 32 + (l >> 4) * 8;
    f32x4 lo = *(const f32x4*)(W + f * FEAT + d0);
    f32x4 hi = *(const f32x4*)(W + f * FEAT + d0 + 4);
    Blds[c] = cvt2(lo, hi);
  }

  float bias[8];
  #pragma unroll
  for (int nt = 0; nt < 8; ++nt) bias[nt] = b[nt * 16 + col];

  __syncthreads();

  const float inv = 1.0f / (float)NSAMP;
  const bool  v1 = col < 9;              // tile-1 row (16+col) valid iff col<9
  const bf16x8 zero8 = {};
  float* osc = &Ot[wib][0];

  for (int n = wid; n < NNODES; n += nW) {
    const int* nb = nbr + n * NSAMP;
    const int i0 = nb[col];
    const int i1 = v1 ? nb[16 + col] : 0;

    // ---- Gather A fragments directly in MFMA layout (16 B per lane per kk)
    bf16x8 A0[4], A1[4];
    if (BF16TAB) {
      const __bf16* r0 = embbf + (long long)i0 * FEAT + coff;
      const __bf16* r1 = embbf + (long long)i1 * FEAT + coff;
      #pragma unroll
      for (int kk = 0; kk < 4; ++kk) {
        A0[kk] = *(const bf16x8*)(r0 + kk * 32);
        A1[kk] = v1 ? *(const bf16x8*)(r1 + kk * 32) : zero8;
      }
    } else {
      const float* r0 = embf32 + (long long)i0 * FEAT + coff;
      const float* r1 = embf32 + (long long)i1 * FEAT + coff;
      const f32x4 z = {0.f, 0.f, 0.f, 0.f};
      #pragma unroll
      for (int kk = 0; kk < 4; ++kk) {
        A0[kk] = cvt2(*(const f32x4*)(r0 + kk * 32), *(const f32x4*)(r0 + kk * 32 + 4));
        A1[kk] = v1 ? cvt2(*(const f32x4*)(r1 + kk * 32), *(const f32x4*)(r1 + kk * 32 + 4))
                    : cvt2(z, z);
      }
    }

    #pragma unroll
    for (int nt = 0; nt < 8; ++nt) {
      const float bn = bias[nt];
      f32x4 acc0 = {bn, bn, bn, bn};   // bias folded into C-in
      f32x4 acc1 = {bn, bn, bn, bn};
      #pragma unroll
      for (int kk = 0; kk < 4; ++kk) {
        const bf16x8 Bf = Blds[nt * 256 + kk * 64 + lane];
        acc0 = __builtin_amdgcn_mfma_f32_16x16x32_bf16(A0[kk], Bf, acc0, 0, 0, 0);
        acc1 = __builtin_amdgcn_mfma_f32_16x16x32_bf16(A1[kk], Bf, acc1, 0, 0, 0);
      }
      // relu + per-lane partial mean-pool (pad rows contribute relu(bias))
      float psum = 0.f;
      #pragma unroll
      for (int j = 0; j < 4; ++j)
        psum += fmaxf(acc0[j], 0.f) + fmaxf(acc1[j], 0.f);
      psum += __shfl_xor(psum, 16);
      psum += __shfl_xor(psum, 32);
      if (lane < 16)
        osc[nt * 16 + lane] = (psum - 7.0f * fmaxf(bn, 0.f)) * inv;
    }
    // DS ops are in-order within a wave; drain writes before transpose read
    asm volatile("s_waitcnt lgkmcnt(0)" ::: "memory");
    const f32x2 o2 = *(const f32x2*)(osc + 2 * lane);
    *(f32x2*)(out + (long long)n * FEAT + 2 * lane) = o2;  // 512 B coalesced/node
  }
}

extern "C" void kernel_launch(void* const* d_in, const int* in_sizes, int n_in,
                              void* d_out, int out_size, void* d_ws, size_t ws_size,
                              hipStream_t stream) {
  const int*   nbr = (const int*)d_in[0];
  const float* emb = (const float*)d_in[1];
  const float* W   = (const float*)d_in[2];
  const float* b   = (const float*)d_in[3];
  float* out = (float*)d_out;

  const size_t tabBytes = (size_t)TABROWS * FEAT * sizeof(__bf16);
  const bool useBf16 = ws_size >= tabBytes;

  if (useBf16) {
    __bf16* tab = (__bf16*)d_ws;
    const int n8 = TABROWS * FEAT / 8;
    hipLaunchKernelGGL(cvt_table_kernel, dim3(2048), dim3(256), 0, stream,
                       emb, tab, n8);
    hipLaunchKernelGGL((meanpool_mfma_kernel<1>), dim3(1024), dim3(512), 0, stream,
                       nbr, emb, tab, W, b, out);
  } else {
    hipLaunchKernelGGL((meanpool_mfma_kernel<0>), dim3(1024), dim3(512), 0, stream,
                       nbr, emb, (const __bf16*)nullptr, W, b, out);
  }
}

// Round 10
// 175.045 us; speedup vs baseline: 1.3097x; 1.2558x over previous
//
#include <hip/hip_runtime.h>
#include <hip/hip_bf16.h>

#define NNODES  50000
#define NGROUPS 25000     // 2 nodes per group
#define NSAMP   25
#define FEAT    128
#define TABROWS 100000

typedef __attribute__((ext_vector_type(4))) float  f32x4;
typedef __attribute__((ext_vector_type(2))) float  f32x2;
typedef __attribute__((ext_vector_type(8))) __bf16 bf16x8;

__device__ __forceinline__ bf16x8 cvt2(const f32x4 lo, const f32x4 hi) {
  bf16x8 r;
  r[0] = (__bf16)lo[0]; r[1] = (__bf16)lo[1];
  r[2] = (__bf16)lo[2]; r[3] = (__bf16)lo[3];
  r[4] = (__bf16)hi[0]; r[5] = (__bf16)hi[1];
  r[6] = (__bf16)hi[2]; r[7] = (__bf16)hi[3];
  return r;
}

// Pass 1: fp32 table -> bf16 table in workspace (halves gather traffic).
__global__ __launch_bounds__(256)
void cvt_table_kernel(const float* __restrict__ src, __bf16* __restrict__ dst, int n8)
{
  int i = blockIdx.x * blockDim.x + threadIdx.x;
  const int stride = gridDim.x * blockDim.x;
  for (; i < n8; i += stride) {
    f32x4 lo = ((const f32x4*)src)[2 * i];
    f32x4 hi = ((const f32x4*)src)[2 * i + 1];
    ((bf16x8*)dst)[i] = cvt2(lo, hi);
  }
}

// Pass 2 (T3-lite): block = 4 waves, group = 2 nodes.
//   out[n,f] = (1/25) * sum_s relu(e[nbr[n,s],:] @ W[f,:] + b[f])
// A (gathered rows, 2 nodes x 32 padded rows x 256 B) lives in LDS,
// DOUBLE-BUFFERED, staged by global_load_lds (16 B/lane): the prefetch for
// group g+1 is issued before computing group g, so gather latency hides
// under a full group of MFMA work -- pipeline state is in LDS, where the
// register allocator can't destroy it (R5/R6/R8/R9 all died to VGPR games).
// B (=W^T) is column-sliced: wave w holds col-tiles {2w,2w+1} in 32 VGPRs;
// B never touches LDS. A-fragment reads use an XOR swizzle (16B-slot ^
// (row&7)), applied to the GLOBAL source address at stage time (LDS dest of
// global_load_lds must stay linear) and to the LDS address at read time,
// spreading the 256B-stride row reads across 8 bank-groups.
// Pad rows (s>=25): staged clamped/stale, zeroed in registers after ds_read
// (col>=9 mask); bias folded into MFMA C-in; 7*relu(bias) correction after
// the reduce. Each wave stores a 128 B aligned full-line slice per node.
// mfma_f32_16x16x32_bf16; C/D: col=lane&15, row=(lane>>4)*4+reg.
__global__ __launch_bounds__(256)
void meanpool_staged_kernel(const int* __restrict__ nbr,
                            const __bf16* __restrict__ tab,
                            const float* __restrict__ W,
                            const float* __restrict__ bb,
                            float* __restrict__ out,
                            int gpb)
{
  __shared__ __align__(16) __bf16 Abuf[2][64][FEAT];   // 2 x 16 KB

  const int tid  = threadIdx.x;
  const int lane = tid & 63;
  const int wib  = tid >> 6;          // wave 0..3 owns output cols [wib*32, wib*32+32)
  const int col  = lane & 15;
  const int quad = lane >> 4;
  const int coff = quad * 8;

  const int g0   = blockIdx.x * gpb;
  const int gEnd = min(g0 + gpb, NGROUPS);
  if (g0 >= gEnd) return;             // uniform per block: no barrier divergence

  // ---- register-resident B slice (2 col-tiles = 32 VGPR) + bias
  bf16x8 Bf[2][4];
  float  bias[2];
  #pragma unroll
  for (int ntl = 0; ntl < 2; ++ntl) {
    const int f = (wib * 2 + ntl) * 16 + col;
    bias[ntl] = bb[f];
    const float* wrow = W + f * FEAT;
    #pragma unroll
    for (int kk = 0; kk < 4; ++kk)
      Bf[ntl][kk] = cvt2(*(const f32x4*)(wrow + kk * 32 + coff),
                         *(const f32x4*)(wrow + kk * 32 + coff + 4));
  }

  const float  inv   = 1.0f / (float)NSAMP;
  const bool   v1    = col < 9;       // odd-tile row (16+col) valid iff col<9
  const bf16x8 zero8 = {};
  const __bf16* lb0 = &Abuf[0][0][0];
  const __bf16* lb1 = &Abuf[1][0][0];

  // 14 stage-chunks per group (7 per node, 4 rows each); wave w: {w,w+4,w+8,w+12}
  auto load_idx = [&](int g, int (&ix)[4]) {
    #pragma unroll
    for (int q = 0; q < 4; ++q) {
      const int c = wib + 4 * q;
      if (c < 14) {
        const int node = (c >= 7) ? 1 : 0;
        const int crow = (c - node * 7) * 4;
        const int samp = min(crow + (lane >> 4), NSAMP - 1);   // clamp pad rows
        ix[q] = nbr[(2 * g + node) * NSAMP + samp];
      }
    }
  };

  auto stage = [&](int buf, const int (&ix)[4]) {
    #pragma unroll
    for (int q = 0; q < 4; ++q) {
      const int c = wib + 4 * q;
      if (c < 14) {
        const int node = (c >= 7) ? 1 : 0;
        const int crow = (c - node * 7) * 4;
        const int r    = node * 32 + crow + (lane >> 4);
        const int cg   = (lane & 15) ^ (r & 7);               // pre-swizzled source
        const __bf16* gp = tab + (long long)ix[q] * FEAT + cg * 8;
        const __bf16* lp = &Abuf[buf][node * 32 + crow][0];   // wave-uniform; HW adds lane*16
        __builtin_amdgcn_global_load_lds(
            (const __attribute__((address_space(1))) void*)gp,
            (__attribute__((address_space(3))) void*)lp, 16, 0, 0);
      }
    }
  };

  auto compute = [&](const __bf16* lb, int g) {
    float ps00 = 0.f, ps01 = 0.f, ps10 = 0.f, ps11 = 0.f;   // [node][ntl]
    #pragma unroll
    for (int m = 0; m < 4; ++m) {
      bf16x8 A[4];
      #pragma unroll
      for (int kk = 0; kk < 4; ++kk) {
        // swizzled read: row = m*16+col, 16B slot = (kk*4+quad) ^ (row&7)
        A[kk] = *(const bf16x8*)(lb + (m * 16 + col) * FEAT +
                                 ((((kk << 2) + quad) ^ (col & 7)) << 3));
        if (m & 1) A[kk] = v1 ? A[kk] : zero8;   // mask pad rows (s>=25)
      }
      #pragma unroll
      for (int ntl = 0; ntl < 2; ++ntl) {
        const float bn = bias[ntl];
        f32x4 acc = {bn, bn, bn, bn};            // bias folded into C-in
        #pragma unroll
        for (int kk = 0; kk < 4; ++kk)
          acc = __builtin_amdgcn_mfma_f32_16x16x32_bf16(A[kk], Bf[ntl][kk], acc, 0, 0, 0);
        const float s = fmaxf(acc[0], 0.f) + fmaxf(acc[1], 0.f) +
                        fmaxf(acc[2], 0.f) + fmaxf(acc[3], 0.f);
        if (m < 2) { if (ntl == 0) ps00 += s; else ps01 += s; }
        else       { if (ntl == 0) ps10 += s; else ps11 += s; }
      }
    }
    // reduce + full-line store per node: wave w writes out[n, w*32 .. w*32+31]
    #pragma unroll
    for (int nd = 0; nd < 2; ++nd) {
      float p0 = nd ? ps10 : ps00;
      float p1 = nd ? ps11 : ps01;
      p0 += __shfl_xor(p0, 16);  p0 += __shfl_xor(p0, 32);
      p1 += __shfl_xor(p1, 16);  p1 += __shfl_xor(p1, 32);
      p0 = (p0 - 7.0f * fmaxf(bias[0], 0.f)) * inv;   // 7 pad rows -> relu(bias)
      p1 = (p1 - 7.0f * fmaxf(bias[1], 0.f)) * inv;
      const int s0 = (2 * lane) & 15, s1 = (2 * lane + 1) & 15;
      const float t0 = __shfl(p0, s0), t1 = __shfl(p0, s1);
      const float t2 = __shfl(p1, s0), t3 = __shfl(p1, s1);
      const bool hi = (lane & 8) != 0;
      f32x2 o;
      o[0] = hi ? t2 : t0;
      o[1] = hi ? t3 : t1;
      if (lane < 16)   // 16 lanes x 8 B = 128 B aligned full line
        *(f32x2*)(out + (long long)(2 * g + nd) * FEAT + wib * 32 + 2 * lane) = o;
    }
  };

  // ---- prologue: stage group g0 into buf0; idx for g0+1 in flight
  int ixA[4] = {0, 0, 0, 0}, ixB[4] = {0, 0, 0, 0};
  load_idx(g0, ixA);
  stage(0, ixA);
  if (g0 + 1 < gEnd) load_idx(g0 + 1, ixB);
  __syncthreads();   // drains stage(g0) (vmcnt0) + barrier

  // ---- steady state, unrolled by 2 (named idx ping-pong, static indexing)
  int cur = 0;
  for (int g = g0; g < gEnd; g += 2) {
    if (g + 1 < gEnd) stage(cur ^ 1, ixB);      // prefetch next group
    if (g + 2 < gEnd) load_idx(g + 2, ixA);     // prefetch next-next indices
    compute(cur ? lb1 : lb0, g);                // rows landed during prev group
    __syncthreads();
    cur ^= 1;
    if (g + 1 >= gEnd) break;
    if (g + 2 < gEnd) stage(cur ^ 1, ixA);
    if (g + 3 < gEnd) load_idx(g + 3, ixB);
    compute(cur ? lb1 : lb0, g + 1);
    __syncthreads();
    cur ^= 1;
  }
}

// Fallback (fp32 table direct-gather; R4's verified loop). Only used if the
// workspace can't hold the bf16 table.
__global__ __launch_bounds__(256, 4)
void meanpool_fallback_kernel(const int* __restrict__ nbr,
                              const float* __restrict__ emb,
                              const float* __restrict__ W,
                              const float* __restrict__ b,
                              float* __restrict__ out)
{
  __shared__ bf16x8 Blds[8 * 4 * 64];
  __shared__ float  Ot[4][128];

  const int tid = threadIdx.x, lane = tid & 63, wib = tid >> 6;
  const int wid = blockIdx.x * 4 + wib, nW = gridDim.x * 4;
  const int col = lane & 15, quad = lane >> 4, coff = quad * 8;

  for (int c = tid; c < 2048; c += 256) {
    const int nt = c >> 8, kk = (c >> 6) & 3, l = c & 63;
    const int f = nt * 16 + (l & 15), d0 = kk * 32 + (l >> 4) * 8;
    Blds[c] = cvt2(*(const f32x4*)(W + f * FEAT + d0),
                   *(const f32x4*)(W + f * FEAT + d0 + 4));
  }
  float bias[8];
  #pragma unroll
  for (int nt = 0; nt < 8; ++nt) bias[nt] = b[nt * 16 + col];
  __syncthreads();

  const float inv = 1.0f / (float)NSAMP;
  const bool  v1 = col < 9;
  float* osc = &Ot[wib][0];

  for (int n = wid; n < NNODES; n += nW) {
    const int* nb = nbr + n * NSAMP;
    const int i0 = nb[col];
    const int i1 = v1 ? nb[16 + col] : 0;
    const float* r0 = emb + (long long)i0 * FEAT + coff;
    const float* r1 = emb + (long long)i1 * FEAT + coff;
    const f32x4 z = {0.f, 0.f, 0.f, 0.f};
    bf16x8 A0[4], A1[4];
    #pragma unroll
    for (int kk = 0; kk < 4; ++kk) {
      A0[kk] = cvt2(*(const f32x4*)(r0 + kk * 32), *(const f32x4*)(r0 + kk * 32 + 4));
      A1[kk] = v1 ? cvt2(*(const f32x4*)(r1 + kk * 32), *(const f32x4*)(r1 + kk * 32 + 4))
                  : cvt2(z, z);
    }
    #pragma unroll
    for (int nt = 0; nt < 8; ++nt) {
      const float bn = bias[nt];
      f32x4 a0 = {bn, bn, bn, bn}, a1 = {bn, bn, bn, bn};
      #pragma unroll
      for (int kk = 0; kk < 4; ++kk) {
        const bf16x8 Bfr = Blds[nt * 256 + kk * 64 + lane];
        a0 = __builtin_amdgcn_mfma_f32_16x16x32_bf16(A0[kk], Bfr, a0, 0, 0, 0);
        a1 = __builtin_amdgcn_mfma_f32_16x16x32_bf16(A1[kk], Bfr, a1, 0, 0, 0);
      }
      float ps = 0.f;
      #pragma unroll
      for (int j = 0; j < 4; ++j) ps += fmaxf(a0[j], 0.f) + fmaxf(a1[j], 0.f);
      ps += __shfl_xor(ps, 16);
      ps += __shfl_xor(ps, 32);
      if (lane < 16) osc[nt * 16 + lane] = (ps - 7.0f * fmaxf(bn, 0.f)) * inv;
    }
    asm volatile("s_waitcnt lgkmcnt(0)" ::: "memory");
    const f32x2 o2 = *(const f32x2*)(osc + 2 * lane);
    *(f32x2*)(out + (long long)n * FEAT + 2 * lane) = o2;
  }
}

extern "C" void kernel_launch(void* const* d_in, const int* in_sizes, int n_in,
                              void* d_out, int out_size, void* d_ws, size_t ws_size,
                              hipStream_t stream) {
  const int*   nbr = (const int*)d_in[0];
  const float* emb = (const float*)d_in[1];
  const float* W   = (const float*)d_in[2];
  const float* b   = (const float*)d_in[3];
  float* out = (float*)d_out;

  const size_t tabBytes = (size_t)TABROWS * FEAT * sizeof(__bf16);
  if (ws_size >= tabBytes) {
    __bf16* tab = (__bf16*)d_ws;
    const int n8 = TABROWS * FEAT / 8;
    hipLaunchKernelGGL(cvt_table_kernel, dim3(2048), dim3(256), 0, stream,
                       emb, tab, n8);
    const int gridB = 2048;
    const int gpb   = (NGROUPS + gridB - 1) / gridB;   // 13
    hipLaunchKernelGGL(meanpool_staged_kernel, dim3(gridB), dim3(256), 0, stream,
                       nbr, tab, W, b, out, gpb);
  } else {
    hipLaunchKernelGGL(meanpool_fallback_kernel, dim3(2048), dim3(256), 0, stream,
                       nbr, emb, W, b, out);
  }
}